// Round 10
// baseline (1376.134 us; speedup 1.0000x reference)
//
#include <hip/hip_runtime.h>
#include <hip/hip_bf16.h>

#define NSWEEP_X 8
#define NSWEEP_W 12

typedef float v2f __attribute__((ext_vector_type(2)));

__device__ __forceinline__ void wavefence() {
    __builtin_amdgcn_wave_barrier();
    asm volatile("" ::: "memory");
}

// Packed fp32 (VOP3P) helpers — 2 fp32 per instruction.
__device__ __forceinline__ v2f pk_mul(v2f a, v2f b) {
    v2f d; asm("v_pk_mul_f32 %0, %1, %2" : "=v"(d) : "v"(a), "v"(b)); return d;
}
__device__ __forceinline__ v2f pk_add(v2f a, v2f b) {
    v2f d; asm("v_pk_add_f32 %0, %1, %2" : "=v"(d) : "v"(a), "v"(b)); return d;
}
__device__ __forceinline__ v2f pk_fma(v2f a, v2f b, v2f c) {
    v2f d; asm("v_pk_fma_f32 %0, %1, %2, %3" : "=v"(d) : "v"(a), "v"(b), "v"(c)); return d;
}

__device__ __forceinline__ float bperm(int addr, float v) {
    return __int_as_float(__builtin_amdgcn_ds_bpermute(addr, __float_as_int(v)));
}

// 4-accumulator dot of two 32-float columns held as v2f[16]; dep chain ~4 FMA
// deep instead of 16 (r9 was a serial 16-FMA chain on the critical path).
__device__ __forceinline__ float dot32(const v2f a[16], const v2f b[16]) {
    v2f s0 = pk_mul(a[0], b[0]), s1 = pk_mul(a[1], b[1]);
    v2f s2 = pk_mul(a[2], b[2]), s3 = pk_mul(a[3], b[3]);
#pragma unroll
    for (int i = 4; i < 16; i += 4) {
        s0 = pk_fma(a[i+0], b[i+0], s0);
        s1 = pk_fma(a[i+1], b[i+1], s1);
        s2 = pk_fma(a[i+2], b[i+2], s2);
        s3 = pk_fma(a[i+3], b[i+3], s3);
    }
    v2f s = pk_add(pk_add(s0, s1), pk_add(s2, s3));
    return s.x + s.y;
}

// One-sided Jacobi, FULL column per lane, TWO matrices per wave:
// lanes 0-31 = matrix A columns, lanes 32-63 = matrix B (independent).
// XOR ordering (m=1..31) stays within each 32-lane half. Pair dot cp is
// lane-local. Local-tau update (r7-r9 proven): side-uniform col' =
// c*col - s*prt, nn' = nn - t*cp; bitwise-equal cp across the pair.
// Absolute skip threshold (4e-6*nmax)^2 above fp32 dot noise -> the
// all-skip early exit fires once converged.
// NOTE: keep the m-loop ROLLED — full unroll spills (round-3 regression).
__device__ __forceinline__ void jacobi2(v2f col[16], int lane, int nsweep) {
    const int lb = lane << 2;
    for (int sw = 0; sw < nsweep; ++sw) {
        float nn = dot32(col, col);          // own-column norm^2 (lane-local)
        float nmax = nn;                     // per-matrix max (32-group butterfly)
#pragma unroll
        for (int mk = 16; mk >= 1; mk >>= 1) nmax = fmaxf(nmax, __shfl_xor(nmax, mk));
        const float thr = 1.6e-11f * nmax * nmax;   // (4e-6 * nmax)^2

        int did = 0;
#pragma unroll 1
        for (int m = 1; m < 32; ++m) {
            const int addr = lb ^ (m << 2);  // stays within own 32-lane half
            v2f prt[16];
#pragma unroll
            for (int i = 0; i < 16; i++) {
                prt[i].x = bperm(addr, col[i].x);
                prt[i].y = bperm(addr, col[i].y);
            }
            float on = bperm(addr, nn);      // partner norm^2
            float cp = dot32(col, prt);      // full pair dot, lane-local
            if (cp * cp > thr) {
                float tau = (on - nn) * __builtin_amdgcn_rcpf(2.0f * cp);
                float den = fabsf(tau) + __builtin_amdgcn_sqrtf(fmaf(tau, tau, 1.0f));
                float tt  = copysignf(__builtin_amdgcn_rcpf(den), tau);
                float cth = __builtin_amdgcn_rsqf(fmaf(tt, tt, 1.0f));
                float msn = tt * (-cth);
                v2f cs2; cs2.x = cth; cs2.y = cth;
                v2f ms2; ms2.x = msn; ms2.y = msn;
#pragma unroll
                for (int i = 0; i < 16; i++)
                    col[i] = pk_fma(ms2, prt[i], pk_mul(cs2, col[i]));
                nn = fmaxf(fmaf(-tt, cp, nn), 0.0f);
                did = 1;
            }
        }
        if (!__any(did)) break;   // both matrices converged
    }
}

// Rank own column by sigma^2 (descending, tie-break index) within the 32-lane
// group; rk<8 lanes pack their column into P0m[rk*32 + h], sigma^2 into sigm.
__device__ __forceinline__ void rank_pack2(const v2f col[16], int jl,
                                           float* P0m, float* nrmm, float* sigm) {
    float nn = dot32(col, col);
    nrmm[jl] = nn;
    wavefence();
    int rk = 0;
    for (int k = 0; k < 32; k++) {
        float o = nrmm[k];
        rk += (o > nn) || (o == nn && k < jl);
    }
    if (rk < 8) {
#pragma unroll
        for (int i = 0; i < 16; i++)
            *(v2f*)&P0m[rk * 32 + 2 * i] = col[i];
        sigm[rk] = nn;
    }
    wavefence();
}

// ---- Kernel 1: SVD of w[c]; one wave per block handles TWO c channels.
//   uwd[c][h][m] = Uw[h][m]*dw[m]   (converged column)
//   vwt[c][w][m] = Vwh[m][w]        (A0^T a_m / sigma_m^2)
__global__ __launch_bounds__(64)
void svd_w_kernel(const float* __restrict__ w, float* __restrict__ uwd,
                  float* __restrict__ vwt) {
    __shared__ float P0w[512];   // [hb*256 + mm*32 + h]
    __shared__ float nrmw[64];
    __shared__ float sigw[16];
    const int lane = threadIdx.x, jl = lane & 31, hb = lane >> 5;
    const int c = blockIdx.x * 2 + hb;

    v2f col[16], a0[16];
#pragma unroll
    for (int i = 0; i < 16; i++) {
        col[i].x = w[c * 1024 + (2 * i) * 32 + jl];
        col[i].y = w[c * 1024 + (2 * i + 1) * 32 + jl];
        a0[i] = col[i];
    }
    jacobi2(col, lane, NSWEEP_W);
    rank_pack2(col, jl, P0w + hb * 256, nrmw + hb * 32, sigw + hb * 8);

    for (int e = jl; e < 256; e += 32)
        uwd[c * 256 + e] = P0w[hb * 256 + (e & 7) * 32 + (e >> 3)];

#pragma unroll
    for (int mm = 0; mm < 8; mm++) {
        v2f p[16];
#pragma unroll
        for (int i = 0; i < 16; i++) p[i] = *(const v2f*)&P0w[hb * 256 + mm * 32 + 2 * i];
        float vq = dot32(a0, p);
        vq *= __builtin_amdgcn_rcpf(sigw[hb * 8 + mm]);
        vwt[c * 256 + jl * 8 + mm] = vq;
    }
}

// ---- Kernel 2: block = 4 waves = 8 matrices (8 c of one bt). grid 4096.
// NO LDS staging: columns load straight from global (L3 absorbs the strided
// overfetch; input fits in 256MB L3). a0 re-loaded from global after Jacobi
// into the registers freed by prt -> peak liveness ~col+prt (fits 80 VGPR).
// LDS = P0(8K) + nrm(1K) + sig(.25K) + OUT(8K quarter-pass) = 17.25KB ->
// 6 blocks/CU at launch_bounds(256,6): 24 waves/CU vs r9's 14.
__global__ __launch_bounds__(256, 6)
void svd_main_kernel(const float* __restrict__ x, const float* __restrict__ uwd,
                     const float* __restrict__ vwt, float* __restrict__ out) {
    __shared__ float P0[2048];    // [mi*256 + mm*32 + h]
    __shared__ float nrm[256];    // [mi*32 + j]
    __shared__ float sig[64];     // [mi*8 + mm]
    __shared__ float OUT[2048];   // [mi*256 + r*32 + wj]  (8-row quarter-pass)

    const int t = threadIdx.x, widx = t >> 6, lane = t & 63;
    const int jl = lane & 31, hb = lane >> 5;
    const int bt = blockIdx.x & 1023, cg = blockIdx.x >> 10;
    const int mi = widx * 2 + hb, c = cg * 8 + mi;

    // own column straight from global: x[bt][h][jl][c], h stride 1024 floats
    const float* xb = x + (size_t)bt * 32768 + (size_t)jl * 32 + c;
    v2f col[16];
#pragma unroll
    for (int i = 0; i < 16; i++) {
        col[i].x = xb[(2 * i) * 1024];
        col[i].y = xb[(2 * i + 1) * 1024];
    }

    jacobi2(col, lane, NSWEEP_X);
    rank_pack2(col, jl, P0 + mi * 256, nrm + mi * 32, sig + mi * 8);
    // col dead; re-load original column (L3-hot) for the V recovery

    v2f a0[16];
#pragma unroll
    for (int i = 0; i < 16; i++) {
        a0[i].x = xb[(2 * i) * 1024];
        a0[i].y = xb[(2 * i + 1) * 1024];
    }

    // qv[mm] = (A0^T a_mm / sigma^2) * vw   (lane jl = V-row index w)
    const float* vw = vwt + c * 256;
    const float* uw = uwd + c * 256;
    float qv[8];
#pragma unroll
    for (int mm = 0; mm < 8; mm++) {
        v2f p[16];
#pragma unroll
        for (int i = 0; i < 16; i++) p[i] = *(const v2f*)&P0[mi * 256 + mm * 32 + 2 * i];
        float vq = dot32(a0, p);
        vq *= __builtin_amdgcn_rcpf(sig[mi * 8 + mm]);
        qv[mm] = vq * vw[jl * 8 + mm];
    }

    // Pg in place: P0[mm*32+h] *= uw[h*8+mm]
    for (int e = jl; e < 256; e += 32)
        P0[mi * 256 + e] *= uw[(e & 31) * 8 + (e >> 5)];
    wavefence();

    // out[h][jl] = sum_mm Pg[h][mm]*qv[mm], in four 8-row quarter-passes.
    float4* o4 = (float4*)out;
    const size_t obase = (size_t)bt * 8192 + cg * 2;
    for (int p = 0; p < 4; ++p) {
#pragma unroll
        for (int i = 0; i < 8; i++) {
            int h = p * 8 + i;
            float acc = 0.f;
#pragma unroll
            for (int mm = 0; mm < 8; mm++)
                acc = fmaf(P0[mi * 256 + mm * 32 + h], qv[mm], acc);
            OUT[mi * 256 + i * 32 + jl] = acc;
        }
        __syncthreads();
        {
            int hh = t >> 5, wj = t & 31;         // 8 rows x 32 cols
            int h = p * 8 + hh;
            float4 v0 = make_float4(OUT[t], OUT[256 + t], OUT[512 + t], OUT[768 + t]);
            float4 v1 = make_float4(OUT[1024 + t], OUT[1280 + t], OUT[1536 + t], OUT[1792 + t]);
            o4[obase + (size_t)(h * 256 + wj * 8)]     = v0;
            o4[obase + (size_t)(h * 256 + wj * 8) + 1] = v1;
        }
        if (p < 3) __syncthreads();   // stores read OUT before next pass rewrites
    }
}

extern "C" void kernel_launch(void* const* d_in, const int* in_sizes, int n_in,
                              void* d_out, int out_size, void* d_ws, size_t ws_size,
                              hipStream_t stream) {
    (void)in_sizes; (void)n_in; (void)out_size; (void)ws_size;
    const float* x = (const float*)d_in[0];
    const float* w = (const float*)d_in[1];
    float* out = (float*)d_out;
    float* uwd = (float*)d_ws;            // [32][32][8]
    float* vwt = uwd + 32 * 256;          // [32][32][8]

    hipLaunchKernelGGL(svd_w_kernel, dim3(16), dim3(64), 0, stream, w, uwd, vwt);
    hipLaunchKernelGGL(svd_main_kernel, dim3(4096), dim3(256), 0, stream, x, uwd, vwt, out);
}